// Round 1
// baseline (373.598 us; speedup 1.0000x reference)
//
#include <hip/hip_runtime.h>
#include <math.h>

#define NN 2048
#define NH 16
#define HSZ 32
#define INF_ 256

__device__ __forceinline__ float atomicMaxF(float* addr, float val) {
    int* ia = (int*)addr;
    int old = __float_as_int(*addr);
    while (__int_as_float(old) < val) {
        int assumed = old;
        old = atomicCAS(ia, assumed, __float_as_int(val));
        if (old == assumed) break;
    }
    return __int_as_float(old);
}

// feat = x @ W  ([NN,K]@[K,32]), plus el/er = sum_d feat[n,h,d]*a{l,r}[h,d]
template<int K>
__global__ void k_gat_feat(const float* __restrict__ x, const float* __restrict__ W,
                           const float* __restrict__ al, const float* __restrict__ ar,
                           float* __restrict__ feat, float* __restrict__ el,
                           float* __restrict__ er) {
    __shared__ float xs[8 * K];
    __shared__ float fs[8 * HSZ];
    int tid = threadIdx.x;
    int row0 = blockIdx.x * 8;
    for (int i = tid; i < 8 * K; i += 256) xs[i] = x[(size_t)row0 * K + i];
    __syncthreads();
    int r = tid >> 5, j = tid & 31;
    float acc = 0.f;
#pragma unroll 8
    for (int k = 0; k < K; ++k) acc += xs[r * K + k] * W[k * HSZ + j];
    fs[r * HSZ + j] = acc;
    feat[(size_t)(row0 + r) * HSZ + j] = acc;
    __syncthreads();
    if (tid < 128) {
        int rr = tid >> 4, hh = tid & 15;
        el[(row0 + rr) * NH + hh] =
            fs[rr * HSZ + 2 * hh] * al[2 * hh] + fs[rr * HSZ + 2 * hh + 1] * al[2 * hh + 1];
    } else {
        int t = tid - 128;
        int rr = t >> 4, hh = t & 15;
        er[(row0 + rr) * NH + hh] =
            fs[rr * HSZ + 2 * hh] * ar[2 * hh] + fs[rr * HSZ + 2 * hh + 1] * ar[2 * hh + 1];
    }
}

__global__ void k_init(float* __restrict__ m, float* __restrict__ s, float* __restrict__ acc) {
    int i = blockIdx.x * 256 + threadIdx.x;
    if (i < NN * NH) {
        m[i] = -1e30f;
        s[i] = 0.f;
        acc[2 * i] = 0.f;
        acc[2 * i + 1] = 0.f;
    }
}

__global__ void k_edge_max(int EH, const int* __restrict__ src, const int* __restrict__ dst,
                           const float* __restrict__ el, const float* __restrict__ er,
                           float* __restrict__ m) {
    int i = blockIdx.x * 256 + threadIdx.x;
    if (i >= EH) return;
    int e = i >> 4, hh = i & 15;
    int sV = src[e], dV = dst[e];
    float v = el[sV * NH + hh] + er[dV * NH + hh];
    v = v > 0.f ? v : 0.2f * v;
    atomicMaxF(&m[dV * NH + hh], v);
}

__global__ void k_edge_acc(int EH, const int* __restrict__ src, const int* __restrict__ dst,
                           const float* __restrict__ el, const float* __restrict__ er,
                           const float* __restrict__ feat, const float* __restrict__ m,
                           float* __restrict__ ssum, float* __restrict__ acc) {
    int i = blockIdx.x * 256 + threadIdx.x;
    if (i >= EH) return;
    int e = i >> 4, hh = i & 15;
    int sV = src[e], dV = dst[e];
    float v = el[sV * NH + hh] + er[dV * NH + hh];
    v = v > 0.f ? v : 0.2f * v;
    float ex = __expf(v - m[dV * NH + hh]);
    atomicAdd(&ssum[dV * NH + hh], ex);
    atomicAdd(&acc[(dV * NH + hh) * 2 + 0], ex * feat[sV * HSZ + 2 * hh]);
    atomicAdd(&acc[(dV * NH + hh) * 2 + 1], ex * feat[sV * HSZ + 2 * hh + 1]);
}

__global__ void k_node_out(const float* __restrict__ acc, const float* __restrict__ ssum,
                           const float* __restrict__ bias, float* __restrict__ hout) {
    int i = blockIdx.x * 256 + threadIdx.x;
    if (i >= NN * HSZ) return;
    int n = i >> 5, j = i & 31;
    hout[i] = acc[i] / ssum[n * NH + (j >> 1)] + bias[j];
}

__global__ void k_qkv(const float* __restrict__ h, const float* __restrict__ qw,
                      const float* __restrict__ qb, const float* __restrict__ kw,
                      const float* __restrict__ kb, const float* __restrict__ vw,
                      const float* __restrict__ vb, float* __restrict__ Q,
                      float* __restrict__ Kt, float* __restrict__ Vt) {
    int i = blockIdx.x * 256 + threadIdx.x;  // NN*HSZ threads
    int n = i >> 5, j = i & 31;
    float q = qb[j], k = kb[j], v = vb[j];
#pragma unroll
    for (int c = 0; c < HSZ; ++c) {
        float hv = h[n * HSZ + c];
        q += hv * qw[c * HSZ + j];
        k += hv * kw[c * HSZ + j];
        v += hv * vw[c * HSZ + j];
    }
    Q[i] = q;
    int hh = j >> 1, d = j & 1;
    Kt[hh * (NN * 2) + n * 2 + d] = k;
    Vt[hh * (NN * 2) + n * 2 + d] = v;
}

// one block = (head hh = blockIdx.y, 256 query rows). K_h,V_h staged in LDS.
__global__ void k_attn(const float* __restrict__ Q, const float* __restrict__ Kt,
                       const float* __restrict__ Vt, float* __restrict__ ao) {
    __shared__ float kh[NN * 2];
    __shared__ float vh[NN * 2];
    int tid = threadIdx.x;
    int hh = blockIdx.y;
    int n = blockIdx.x * 256 + tid;
    const float* Kh = Kt + hh * (NN * 2);
    const float* Vh = Vt + hh * (NN * 2);
    for (int i = tid; i < NN * 2; i += 256) {
        kh[i] = Kh[i];
        vh[i] = Vh[i];
    }
    __syncthreads();
    const float inv = 0.70710678118654752f;  // 1/sqrt(D=2)
    float q0 = Q[n * HSZ + hh * 2] * inv;
    float q1 = Q[n * HSZ + hh * 2 + 1] * inv;
    float mx = -1e30f;
    for (int mm = 0; mm < NN; ++mm) {
        float s = q0 * kh[2 * mm] + q1 * kh[2 * mm + 1];
        mx = fmaxf(mx, s);
    }
    float sum = 0.f, a0 = 0.f, a1 = 0.f;
    for (int mm = 0; mm < NN; ++mm) {
        float s = q0 * kh[2 * mm] + q1 * kh[2 * mm + 1];
        float p = __expf(s - mx);
        sum += p;
        a0 += p * vh[2 * mm];
        a1 += p * vh[2 * mm + 1];
    }
    float rs = 1.f / sum;
    ao[n * HSZ + hh * 2] = a0 * rs;
    ao[n * HSZ + hh * 2 + 1] = a1 * rs;
}

__global__ void k_oproj(const float* __restrict__ ao, const float* __restrict__ ow,
                        const float* __restrict__ ob, float* __restrict__ X) {
    int i = blockIdx.x * 256 + threadIdx.x;
    int n = i >> 5, j = i & 31;
    float a = ob[j];
#pragma unroll
    for (int c = 0; c < HSZ; ++c) a += ao[n * HSZ + c] * ow[c * HSZ + j];
    X[i] = a;
}

__global__ void k_bn(const float* __restrict__ X, float* __restrict__ mu,
                     float* __restrict__ rstd) {
    __shared__ float s1[256], s2[256];
    int j = blockIdx.x, tid = threadIdx.x;
    float a = 0.f, b = 0.f;
    for (int r = tid; r < NN; r += 256) {
        float v = X[r * HSZ + j];
        a += v;
        b += v * v;
    }
    s1[tid] = a;
    s2[tid] = b;
    __syncthreads();
    for (int s = 128; s > 0; s >>= 1) {
        if (tid < s) {
            s1[tid] += s1[tid + s];
            s2[tid] += s2[tid + s];
        }
        __syncthreads();
    }
    if (tid == 0) {
        float m = s1[0] / NN;
        float var = s2[0] / NN - m * m;
        mu[j] = m;
        rstd[j] = rsqrtf(var + 1e-5f);
    }
}

__global__ void k_tail(const float* __restrict__ X, const float* __restrict__ mu,
                       const float* __restrict__ rstd, const float* __restrict__ bn_g,
                       const float* __restrict__ bn_b, const float* __restrict__ m1w,
                       const float* __restrict__ m1b, const float* __restrict__ m2w,
                       const float* __restrict__ m2b, const float* __restrict__ w001,
                       const float* __restrict__ b001, const float* __restrict__ w01,
                       const float* __restrict__ b01, const float* __restrict__ w1,
                       const float* __restrict__ b1, const float* __restrict__ w2,
                       const float* __restrict__ b2, float* __restrict__ out) {
    int n = blockIdx.x * 256 + threadIdx.x;
    float x[HSZ];
#pragma unroll
    for (int i = 0; i < HSZ; ++i)
        x[i] = (X[n * HSZ + i] - mu[i]) * rstd[i] * bn_g[i] + bn_b[i];
    float y[16];
#pragma unroll
    for (int j = 0; j < 16; ++j) {
        float a = m1b[j];
#pragma unroll
        for (int i = 0; i < HSZ; ++i) a += x[i] * m1w[i * 16 + j];
        y[j] = fmaxf(a, 0.f);
    }
    float z[HSZ];
#pragma unroll
    for (int j = 0; j < HSZ; ++j) {
        float a = m2b[j];
#pragma unroll
        for (int i = 0; i < 16; ++i) a += y[i] * m2w[i * HSZ + j];
        z[j] = fmaxf(a, 0.f);
    }
    float a16[16];
#pragma unroll
    for (int j = 0; j < 16; ++j) {
        float a = b001[j];
#pragma unroll
        for (int i = 0; i < HSZ; ++i) a += z[i] * w001[i * 16 + j];
        a16[j] = a > 0.f ? a : 0.01f * a;
    }
    float b8[8];
#pragma unroll
    for (int j = 0; j < 8; ++j) {
        float a = b01[j];
#pragma unroll
        for (int i = 0; i < 16; ++i) a += a16[i] * w01[i * 8 + j];
        b8[j] = a > 0.f ? a : 0.01f * a;
    }
    float c4[4];
#pragma unroll
    for (int j = 0; j < 4; ++j) {
        float a = b1[j];
#pragma unroll
        for (int i = 0; i < 8; ++i) a += b8[i] * w1[i * 4 + j];
        c4[j] = a > 0.f ? a : 0.01f * a;
    }
    float d = b2[0];
#pragma unroll
    for (int i = 0; i < 4; ++i) d += c4[i] * w2[i];
    out[n] = 1.f / (1.f + __expf(-d));
}

extern "C" void kernel_launch(void* const* d_in, const int* in_sizes, int n_in,
                              void* d_out, int out_size, void* d_ws, size_t ws_size,
                              hipStream_t stream) {
    const float* features = (const float*)d_in[0];
    const int* src = (const int*)d_in[1];
    const int* dst = (const int*)d_in[2];
    const float* W1 = (const float*)d_in[3];
    const float* al1 = (const float*)d_in[4];
    const float* ar1 = (const float*)d_in[5];
    const float* bg1 = (const float*)d_in[6];
    const float* W2 = (const float*)d_in[7];
    const float* al2 = (const float*)d_in[8];
    const float* ar2 = (const float*)d_in[9];
    const float* bg2 = (const float*)d_in[10];
    const float* qw = (const float*)d_in[11];
    const float* qb = (const float*)d_in[12];
    const float* kw = (const float*)d_in[13];
    const float* kb = (const float*)d_in[14];
    const float* vw = (const float*)d_in[15];
    const float* vb = (const float*)d_in[16];
    const float* ow = (const float*)d_in[17];
    const float* ob = (const float*)d_in[18];
    const float* bn_g = (const float*)d_in[19];
    const float* bn_b = (const float*)d_in[20];
    const float* m1w = (const float*)d_in[21];
    const float* m1b = (const float*)d_in[22];
    const float* m2w = (const float*)d_in[23];
    const float* m2b = (const float*)d_in[24];
    const float* w001 = (const float*)d_in[25];
    const float* b001 = (const float*)d_in[26];
    const float* w01 = (const float*)d_in[27];
    const float* b01 = (const float*)d_in[28];
    const float* w1 = (const float*)d_in[29];
    const float* b1 = (const float*)d_in[30];
    const float* w2 = (const float*)d_in[31];
    const float* b2 = (const float*)d_in[32];

    int E = in_sizes[1];
    int EH = E * NH;

    float* ws = (float*)d_ws;
    float* feat = ws;                 // NN*32
    float* el = feat + NN * HSZ;      // NN*16
    float* er = el + NN * NH;         // NN*16
    float* mbuf = er + NN * NH;       // NN*16
    float* ssum = mbuf + NN * NH;     // NN*16
    float* acc = ssum + NN * NH;      // NN*32
    float* h1 = acc + NN * HSZ;       // NN*32
    float* h2 = h1 + NN * HSZ;        // NN*32
    float* Q = h2 + NN * HSZ;         // NN*32
    float* Kt = Q + NN * HSZ;         // NN*32
    float* Vt = Kt + NN * HSZ;        // NN*32
    float* ao = Vt + NN * HSZ;        // NN*32
    float* X = ao + NN * HSZ;         // NN*32
    float* mu = X + NN * HSZ;         // 32
    float* rstd = mu + HSZ;           // 32

    dim3 b256(256);
    int gEH = (EH + 255) / 256;
    int gNH = (NN * NH + 255) / 256;
    int gNHS = (NN * HSZ + 255) / 256;

    // ---- GAT layer 1 ----
    k_gat_feat<INF_><<<NN / 8, b256, 0, stream>>>(features, W1, al1, ar1, feat, el, er);
    k_init<<<gNH, b256, 0, stream>>>(mbuf, ssum, acc);
    k_edge_max<<<gEH, b256, 0, stream>>>(EH, src, dst, el, er, mbuf);
    k_edge_acc<<<gEH, b256, 0, stream>>>(EH, src, dst, el, er, feat, mbuf, ssum, acc);
    k_node_out<<<gNHS, b256, 0, stream>>>(acc, ssum, bg1, h1);

    // ---- GAT layer 2 ----
    k_gat_feat<HSZ><<<NN / 8, b256, 0, stream>>>(h1, W2, al2, ar2, feat, el, er);
    k_init<<<gNH, b256, 0, stream>>>(mbuf, ssum, acc);
    k_edge_max<<<gEH, b256, 0, stream>>>(EH, src, dst, el, er, mbuf);
    k_edge_acc<<<gEH, b256, 0, stream>>>(EH, src, dst, el, er, feat, mbuf, ssum, acc);
    k_node_out<<<gNHS, b256, 0, stream>>>(acc, ssum, bg2, h2);

    // ---- dense MHA ----
    k_qkv<<<gNHS, b256, 0, stream>>>(h2, qw, qb, kw, kb, vw, vb, Q, Kt, Vt);
    dim3 ag(NN / 256, NH);
    k_attn<<<ag, b256, 0, stream>>>(Q, Kt, Vt, ao);
    k_oproj<<<gNHS, b256, 0, stream>>>(ao, ow, ob, X);

    // ---- BN + MLP + scoring head ----
    k_bn<<<HSZ, b256, 0, stream>>>(X, mu, rstd);
    k_tail<<<NN / 256, b256, 0, stream>>>(X, mu, rstd, bn_g, bn_b, m1w, m1b, m2w, m2b,
                                          w001, b001, w01, b01, w1, b1, w2, b2,
                                          (float*)d_out);
}

// Round 2
// 243.062 us; speedup vs baseline: 1.5370x; 1.5370x over previous
//
#include <hip/hip_runtime.h>
#include <math.h>

#define NN 2048
#define NH 16
#define HSZ 32
#define INF_ 256

// ---- GAT layer 1 feature kernel: one block per row, K=256 split 8 ways ----
// feat[n,:] = x[n,:] @ W ; el/er = head-wise dot with al/ar. Also zeros this
// row's ssum/acc accumulators (harness poisons ws each call).
__global__ void k_gat1(const float* __restrict__ x, const float* __restrict__ W,
                       const float* __restrict__ al, const float* __restrict__ ar,
                       float* __restrict__ feat, float* __restrict__ el,
                       float* __restrict__ er, float* __restrict__ ssum,
                       float* __restrict__ acc) {
    __shared__ float xs[INF_];
    __shared__ float ps[256];
    __shared__ float fs[HSZ];
    int n = blockIdx.x, tid = threadIdx.x;
    xs[tid] = x[(size_t)n * INF_ + tid];
    if (tid < NH) ssum[n * NH + tid] = 0.f;
    if (tid >= 64 && tid < 96) acc[n * HSZ + tid - 64] = 0.f;
    __syncthreads();
    int j = tid & 31, part = tid >> 5;
    float a = 0.f;
#pragma unroll
    for (int kk = 0; kk < 32; ++kk) {
        int k = part * 32 + kk;
        a += xs[k] * W[k * HSZ + j];
    }
    ps[tid] = a;
    __syncthreads();
    if (tid < HSZ) {
        float s = 0.f;
#pragma unroll
        for (int p = 0; p < 8; ++p) s += ps[p * 32 + tid];
        fs[tid] = s;
        feat[n * HSZ + tid] = s;
    }
    __syncthreads();
    if (tid < NH) {
        el[n * NH + tid] = fs[2 * tid] * al[2 * tid] + fs[2 * tid + 1] * al[2 * tid + 1];
    } else if (tid < 2 * NH) {
        int hh = tid - NH;
        er[n * NH + hh] = fs[2 * hh] * ar[2 * hh] + fs[2 * hh + 1] * ar[2 * hh + 1];
    }
}

// ---- edge kernel (no max pass; softmax is shift-invariant, scores are small)
__global__ void k_edge(int EH, const int* __restrict__ src, const int* __restrict__ dst,
                       const float* __restrict__ el, const float* __restrict__ er,
                       const float* __restrict__ feat, float* __restrict__ ssum,
                       float* __restrict__ acc) {
    int i = blockIdx.x * 256 + threadIdx.x;
    if (i >= EH) return;
    int e = i >> 4, hh = i & 15;
    int sV = src[e], dV = dst[e];
    float v = el[sV * NH + hh] + er[dV * NH + hh];
    v = v > 0.f ? v : 0.2f * v;
    float ex = __expf(v);
    float2 f = ((const float2*)feat)[sV * NH + hh];
    atomicAdd(&ssum[dV * NH + hh], ex);
    atomicAdd(&acc[(dV * NH + hh) * 2 + 0], ex * f.x);
    atomicAdd(&acc[(dV * NH + hh) * 2 + 1], ex * f.y);
}

// ---- GAT layer 2: h1 computed on the fly from layer-1 accumulators, 8 rows/blk
__global__ void k_gat2(const float* __restrict__ accA, const float* __restrict__ ssumA,
                       const float* __restrict__ bg1, const float* __restrict__ W,
                       const float* __restrict__ al, const float* __restrict__ ar,
                       float* __restrict__ feat, float* __restrict__ el,
                       float* __restrict__ er, float* __restrict__ ssumB,
                       float* __restrict__ accB) {
    __shared__ float hs[256];
    __shared__ float fs[256];
    int tid = threadIdx.x;
    int row0 = blockIdx.x * 8;
    int r = tid >> 5, j = tid & 31;
    hs[tid] = accA[row0 * HSZ + tid] / ssumA[row0 * NH + r * NH + (j >> 1)] + bg1[j];
    if (tid < 128) ssumB[row0 * NH + tid] = 0.f;
    accB[row0 * HSZ + tid] = 0.f;
    __syncthreads();
    float a = 0.f;
#pragma unroll
    for (int c = 0; c < HSZ; ++c) a += hs[r * HSZ + c] * W[c * HSZ + j];
    fs[tid] = a;
    feat[row0 * HSZ + tid] = a;
    __syncthreads();
    if (tid < 128) {
        int rr = tid >> 4, hh = tid & 15;
        el[(row0 + rr) * NH + hh] =
            fs[rr * HSZ + 2 * hh] * al[2 * hh] + fs[rr * HSZ + 2 * hh + 1] * al[2 * hh + 1];
    } else {
        int t = tid - 128;
        int rr = t >> 4, hh = t & 15;
        er[(row0 + rr) * NH + hh] =
            fs[rr * HSZ + 2 * hh] * ar[2 * hh] + fs[rr * HSZ + 2 * hh + 1] * ar[2 * hh + 1];
    }
}

// ---- QKV projection: h2 on the fly; Q pre-scaled by 1/sqrt(2); K,V in
// [H][N][2] layout. Block 0 zeros the BN partial-sum buffer.
__global__ void k_qkv(const float* __restrict__ accB, const float* __restrict__ ssumB,
                      const float* __restrict__ bg2, const float* __restrict__ qw,
                      const float* __restrict__ qb, const float* __restrict__ kw,
                      const float* __restrict__ kb, const float* __restrict__ vw,
                      const float* __restrict__ vb, float* __restrict__ Q,
                      float* __restrict__ Kt, float* __restrict__ Vt,
                      float* __restrict__ bnbuf) {
    __shared__ float hs[256];
    int tid = threadIdx.x;
    int row0 = blockIdx.x * 8;
    int r = tid >> 5, j = tid & 31;
    int n = row0 + r;
    hs[tid] = accB[row0 * HSZ + tid] / ssumB[row0 * NH + r * NH + (j >> 1)] + bg2[j];
    if (blockIdx.x == 0 && tid < 64) bnbuf[tid] = 0.f;
    __syncthreads();
    float q = qb[j], k = kb[j], v = vb[j];
#pragma unroll
    for (int c = 0; c < HSZ; ++c) {
        float hv = hs[r * HSZ + c];
        q += hv * qw[c * HSZ + j];
        k += hv * kw[c * HSZ + j];
        v += hv * vw[c * HSZ + j];
    }
    Q[n * HSZ + j] = q * 0.70710678118654752f;
    int hh = j >> 1, d = j & 1;
    Kt[hh * (NN * 2) + n * 2 + d] = k;
    Vt[hh * (NN * 2) + n * 2 + d] = v;
}

// ---- attention: one wave per (n, head); 64 lanes split the 2048 keys.
// Single pass (no row-max; scores are tiny), butterfly shfl reduction.
__global__ void k_attn(const float* __restrict__ Q, const float* __restrict__ Kt,
                       const float* __restrict__ Vt, float* __restrict__ ao) {
    int gtid = blockIdx.x * 256 + threadIdx.x;
    int wid = gtid >> 6;
    int lane = gtid & 63;
    int n = wid & (NN - 1);
    int hh = wid >> 11;
    float q0 = Q[n * HSZ + hh * 2];
    float q1 = Q[n * HSZ + hh * 2 + 1];
    const float2* K2 = (const float2*)Kt + hh * NN;
    const float2* V2 = (const float2*)Vt + hh * NN;
    float sum = 0.f, a0 = 0.f, a1 = 0.f;
#pragma unroll 8
    for (int it = 0; it < NN / 64; ++it) {
        int mm = it * 64 + lane;
        float2 kk = K2[mm];
        float2 vv = V2[mm];
        float p = __expf(q0 * kk.x + q1 * kk.y);
        sum += p;
        a0 += p * vv.x;
        a1 += p * vv.y;
    }
#pragma unroll
    for (int off = 32; off > 0; off >>= 1) {
        sum += __shfl_xor(sum, off);
        a0 += __shfl_xor(a0, off);
        a1 += __shfl_xor(a1, off);
    }
    if (lane == 0) {
        float rs = 1.f / sum;
        ao[n * HSZ + hh * 2] = a0 * rs;
        ao[n * HSZ + hh * 2 + 1] = a1 * rs;
    }
}

// ---- O-projection + BN partial column sums (atomics) ----
__global__ void k_oproj(const float* __restrict__ ao, const float* __restrict__ ow,
                        const float* __restrict__ ob, float* __restrict__ X,
                        float* __restrict__ bnbuf) {
    __shared__ float as[256];
    __shared__ float xv[256];
    int tid = threadIdx.x;
    int row0 = blockIdx.x * 8;
    as[tid] = ao[row0 * HSZ + tid];
    __syncthreads();
    int r = tid >> 5, j = tid & 31;
    float a = ob[j];
#pragma unroll
    for (int c = 0; c < HSZ; ++c) a += as[r * HSZ + c] * ow[c * HSZ + j];
    X[(row0 + r) * HSZ + j] = a;
    xv[tid] = a;
    __syncthreads();
    if (tid < HSZ) {
        float s = 0.f, q = 0.f;
#pragma unroll
        for (int rr = 0; rr < 8; ++rr) {
            float v = xv[rr * HSZ + tid];
            s += v;
            q += v * v;
        }
        atomicAdd(&bnbuf[tid], s);
        atomicAdd(&bnbuf[HSZ + tid], q);
    }
}

// ---- BN apply + MLP + scoring head + sigmoid ----
__global__ void k_tail(const float* __restrict__ X, const float* __restrict__ bnbuf,
                       const float* __restrict__ bn_g, const float* __restrict__ bn_b,
                       const float* __restrict__ m1w, const float* __restrict__ m1b,
                       const float* __restrict__ m2w, const float* __restrict__ m2b,
                       const float* __restrict__ w001, const float* __restrict__ b001,
                       const float* __restrict__ w01, const float* __restrict__ b01,
                       const float* __restrict__ w1, const float* __restrict__ b1,
                       const float* __restrict__ w2, const float* __restrict__ b2,
                       float* __restrict__ out) {
    int n = blockIdx.x * 256 + threadIdx.x;
    const float invN = 1.f / NN;
    float x[HSZ];
#pragma unroll
    for (int i = 0; i < HSZ; ++i) {
        float mu = bnbuf[i] * invN;
        float var = bnbuf[HSZ + i] * invN - mu * mu;
        float rstd = rsqrtf(var + 1e-5f);
        x[i] = (X[n * HSZ + i] - mu) * rstd * bn_g[i] + bn_b[i];
    }
    float y[16];
#pragma unroll
    for (int j = 0; j < 16; ++j) {
        float a = m1b[j];
#pragma unroll
        for (int i = 0; i < HSZ; ++i) a += x[i] * m1w[i * 16 + j];
        y[j] = fmaxf(a, 0.f);
    }
    float z[HSZ];
#pragma unroll
    for (int j = 0; j < HSZ; ++j) {
        float a = m2b[j];
#pragma unroll
        for (int i = 0; i < 16; ++i) a += y[i] * m2w[i * HSZ + j];
        z[j] = fmaxf(a, 0.f);
    }
    float a16[16];
#pragma unroll
    for (int j = 0; j < 16; ++j) {
        float a = b001[j];
#pragma unroll
        for (int i = 0; i < HSZ; ++i) a += z[i] * w001[i * 16 + j];
        a16[j] = a > 0.f ? a : 0.01f * a;
    }
    float b8[8];
#pragma unroll
    for (int j = 0; j < 8; ++j) {
        float a = b01[j];
#pragma unroll
        for (int i = 0; i < 16; ++i) a += a16[i] * w01[i * 8 + j];
        b8[j] = a > 0.f ? a : 0.01f * a;
    }
    float c4[4];
#pragma unroll
    for (int j = 0; j < 4; ++j) {
        float a = b1[j];
#pragma unroll
        for (int i = 0; i < 8; ++i) a += b8[i] * w1[i * 4 + j];
        c4[j] = a > 0.f ? a : 0.01f * a;
    }
    float d = b2[0];
#pragma unroll
    for (int i = 0; i < 4; ++i) d += c4[i] * w2[i];
    out[n] = 1.f / (1.f + __expf(-d));
}

extern "C" void kernel_launch(void* const* d_in, const int* in_sizes, int n_in,
                              void* d_out, int out_size, void* d_ws, size_t ws_size,
                              hipStream_t stream) {
    const float* features = (const float*)d_in[0];
    const int* src = (const int*)d_in[1];
    const int* dst = (const int*)d_in[2];
    const float* W1 = (const float*)d_in[3];
    const float* al1 = (const float*)d_in[4];
    const float* ar1 = (const float*)d_in[5];
    const float* bg1 = (const float*)d_in[6];
    const float* W2 = (const float*)d_in[7];
    const float* al2 = (const float*)d_in[8];
    const float* ar2 = (const float*)d_in[9];
    const float* bg2 = (const float*)d_in[10];
    const float* qw = (const float*)d_in[11];
    const float* qb = (const float*)d_in[12];
    const float* kw = (const float*)d_in[13];
    const float* kb = (const float*)d_in[14];
    const float* vw = (const float*)d_in[15];
    const float* vb = (const float*)d_in[16];
    const float* ow = (const float*)d_in[17];
    const float* ob = (const float*)d_in[18];
    const float* bn_g = (const float*)d_in[19];
    const float* bn_b = (const float*)d_in[20];
    const float* m1w = (const float*)d_in[21];
    const float* m1b = (const float*)d_in[22];
    const float* m2w = (const float*)d_in[23];
    const float* m2b = (const float*)d_in[24];
    const float* w001 = (const float*)d_in[25];
    const float* b001 = (const float*)d_in[26];
    const float* w01 = (const float*)d_in[27];
    const float* b01 = (const float*)d_in[28];
    const float* w1 = (const float*)d_in[29];
    const float* b1 = (const float*)d_in[30];
    const float* w2 = (const float*)d_in[31];
    const float* b2 = (const float*)d_in[32];

    int E = in_sizes[1];
    int EH = E * NH;

    float* ws = (float*)d_ws;
    float* feat = ws;                  // NN*32
    float* el = feat + NN * HSZ;       // NN*16
    float* er = el + NN * NH;          // NN*16
    float* ssumA = er + NN * NH;       // NN*16
    float* accA = ssumA + NN * NH;     // NN*32
    float* ssumB = accA + NN * HSZ;    // NN*16
    float* accB = ssumB + NN * NH;     // NN*32
    float* Q = accB + NN * HSZ;        // NN*32
    float* Kt = Q + NN * HSZ;          // NN*32
    float* Vt = Kt + NN * HSZ;         // NN*32
    float* ao = Vt + NN * HSZ;         // NN*32
    float* X = ao + NN * HSZ;          // NN*32
    float* bnbuf = X + NN * HSZ;       // 64

    dim3 b256(256);
    int gEH = (EH + 255) / 256;

    // GAT layer 1
    k_gat1<<<NN, b256, 0, stream>>>(features, W1, al1, ar1, feat, el, er, ssumA, accA);
    k_edge<<<gEH, b256, 0, stream>>>(EH, src, dst, el, er, feat, ssumA, accA);
    // GAT layer 2 (h1 fused in)
    k_gat2<<<NN / 8, b256, 0, stream>>>(accA, ssumA, bg1, W2, al2, ar2, feat, el, er,
                                        ssumB, accB);
    k_edge<<<gEH, b256, 0, stream>>>(EH, src, dst, el, er, feat, ssumB, accB);
    // dense MHA (h2 fused into QKV)
    k_qkv<<<NN / 8, b256, 0, stream>>>(accB, ssumB, bg2, qw, qb, kw, kb, vw, vb,
                                       Q, Kt, Vt, bnbuf);
    k_attn<<<(NN * NH) / 4, b256, 0, stream>>>(Q, Kt, Vt, ao);
    k_oproj<<<NN / 8, b256, 0, stream>>>(ao, ow, ob, X, bnbuf);
    // BN stats folded into bnbuf atomics; apply + MLP + head
    k_tail<<<NN / 256, b256, 0, stream>>>(X, bnbuf, bn_g, bn_b, m1w, m1b, m2w, m2b,
                                          w001, b001, w01, b01, w1, b1, w2, b2,
                                          (float*)d_out);
}

// Round 3
// 217.576 us; speedup vs baseline: 1.7171x; 1.1171x over previous
//
#include <hip/hip_runtime.h>
#include <math.h>

#define NN 2048
#define NH 16
#define HSZ 32
#define INF_ 256

// ---- GAT layer 1: feat = x@W1, el/er; also zeros CSR counters + bnbuf ----
__global__ void k_gat1(const float* __restrict__ x, const float* __restrict__ W,
                       const float* __restrict__ al, const float* __restrict__ ar,
                       float* __restrict__ feat, float* __restrict__ el,
                       float* __restrict__ er, int* __restrict__ cnt,
                       int* __restrict__ cur, float* __restrict__ bnbuf) {
    __shared__ float xs[INF_];
    __shared__ float ps[256];
    __shared__ float fs[HSZ];
    int n = blockIdx.x, tid = threadIdx.x;
    xs[tid] = x[(size_t)n * INF_ + tid];
    if (tid == 0) cnt[n] = 0;
    if (tid == 1) cur[n] = 0;
    if (n == 0 && tid >= 128 && tid < 192) bnbuf[tid - 128] = 0.f;
    __syncthreads();
    int j = tid & 31, part = tid >> 5;
    float a = 0.f;
#pragma unroll
    for (int kk = 0; kk < 32; ++kk) {
        int k = part * 32 + kk;
        a += xs[k] * W[k * HSZ + j];
    }
    ps[tid] = a;
    __syncthreads();
    if (tid < HSZ) {
        float s = 0.f;
#pragma unroll
        for (int p = 0; p < 8; ++p) s += ps[p * 32 + tid];
        fs[tid] = s;
        feat[n * HSZ + tid] = s;
    }
    __syncthreads();
    if (tid < NH) {
        el[n * NH + tid] = fs[2 * tid] * al[2 * tid] + fs[2 * tid + 1] * al[2 * tid + 1];
    } else if (tid < 2 * NH) {
        int hh = tid - NH;
        er[n * NH + hh] = fs[2 * hh] * ar[2 * hh] + fs[2 * hh + 1] * ar[2 * hh + 1];
    }
}

// ---- CSR build: histogram of dst ----
__global__ void k_hist(int E, const int* __restrict__ dst, int* __restrict__ cnt) {
    int i = blockIdx.x * 256 + threadIdx.x;
    if (i < E) atomicAdd(&cnt[dst[i]], 1);
}

// ---- CSR build: exclusive prefix scan over 2048 counters (1 block) ----
__global__ void k_scan(const int* __restrict__ cnt, int* __restrict__ off, int E) {
    __shared__ int ps[256];
    int t = threadIdx.x;
    int base = t * 8;
    int loc[8];
    int s = 0;
#pragma unroll
    for (int j = 0; j < 8; ++j) {
        loc[j] = s;
        s += cnt[base + j];
    }
    ps[t] = s;
    __syncthreads();
    for (int st = 1; st < 256; st <<= 1) {
        int v = (t >= st) ? ps[t - st] : 0;
        __syncthreads();
        ps[t] += v;
        __syncthreads();
    }
    int chunkbase = ps[t] - s;
#pragma unroll
    for (int j = 0; j < 8; ++j) off[base + j] = chunkbase + loc[j];
    if (t == 255) off[NN] = chunkbase + s;
}

// ---- CSR build: scatter src into adjacency (order within segment arbitrary) ----
__global__ void k_scatter(int E, const int* __restrict__ src, const int* __restrict__ dst,
                          const int* __restrict__ off, int* __restrict__ cur,
                          int* __restrict__ adj) {
    int i = blockIdx.x * 256 + threadIdx.x;
    if (i >= E) return;
    int d = dst[i];
    int p = atomicAdd(&cur[d], 1);
    adj[off[d] + p] = src[i];
}

// ---- segment softmax+aggregate: 1 thread per (dst,head), gather via CSR ----
__global__ void k_seg(const int* __restrict__ off, const int* __restrict__ adj,
                      const float* __restrict__ el, const float* __restrict__ er,
                      const float* __restrict__ feat, const float* __restrict__ bias,
                      float* __restrict__ hout) {
    int i = blockIdx.x * 256 + threadIdx.x;
    int n = i >> 4, h = i & 15;
    int o0 = off[n], o1 = off[n + 1];
    float erv = er[n * NH + h];
    float sum = 0.f, a0 = 0.f, a1 = 0.f;
    for (int j = o0; j < o1; ++j) {
        int s = adj[j];
        float v = el[s * NH + h] + erv;
        v = v > 0.f ? v : 0.2f * v;
        float ex = __expf(v);
        float2 f = ((const float2*)feat)[s * NH + h];
        sum += ex;
        a0 += ex * f.x;
        a1 += ex * f.y;
    }
    float rs = 1.f / sum;
    hout[n * HSZ + 2 * h] = a0 * rs + bias[2 * h];
    hout[n * HSZ + 2 * h + 1] = a1 * rs + bias[2 * h + 1];
}

// ---- GAT layer 2 features from h1: 8 rows/block ----
__global__ void k_gat2(const float* __restrict__ h1, const float* __restrict__ W,
                       const float* __restrict__ al, const float* __restrict__ ar,
                       float* __restrict__ feat, float* __restrict__ el,
                       float* __restrict__ er) {
    __shared__ float hs[256];
    __shared__ float fs[256];
    int tid = threadIdx.x;
    int row0 = blockIdx.x * 8;
    int r = tid >> 5, j = tid & 31;
    hs[tid] = h1[row0 * HSZ + tid];
    __syncthreads();
    float a = 0.f;
#pragma unroll
    for (int c = 0; c < HSZ; ++c) a += hs[r * HSZ + c] * W[c * HSZ + j];
    fs[tid] = a;
    feat[row0 * HSZ + tid] = a;
    __syncthreads();
    if (tid < 128) {
        int rr = tid >> 4, hh = tid & 15;
        el[(row0 + rr) * NH + hh] =
            fs[rr * HSZ + 2 * hh] * al[2 * hh] + fs[rr * HSZ + 2 * hh + 1] * al[2 * hh + 1];
    } else {
        int t = tid - 128;
        int rr = t >> 4, hh = t & 15;
        er[(row0 + rr) * NH + hh] =
            fs[rr * HSZ + 2 * hh] * ar[2 * hh] + fs[rr * HSZ + 2 * hh + 1] * ar[2 * hh + 1];
    }
}

// ---- QKV projection; Q pre-scaled by 1/sqrt(2); K,V in [H][N][2] ----
__global__ void k_qkv(const float* __restrict__ h2, const float* __restrict__ qw,
                      const float* __restrict__ qb, const float* __restrict__ kw,
                      const float* __restrict__ kb, const float* __restrict__ vw,
                      const float* __restrict__ vb, float* __restrict__ Q,
                      float* __restrict__ Kt, float* __restrict__ Vt) {
    __shared__ float hs[256];
    int tid = threadIdx.x;
    int row0 = blockIdx.x * 8;
    int r = tid >> 5, j = tid & 31;
    int n = row0 + r;
    hs[tid] = h2[row0 * HSZ + tid];
    __syncthreads();
    float q = qb[j], k = kb[j], v = vb[j];
#pragma unroll
    for (int c = 0; c < HSZ; ++c) {
        float hv = hs[r * HSZ + c];
        q += hv * qw[c * HSZ + j];
        k += hv * kw[c * HSZ + j];
        v += hv * vw[c * HSZ + j];
    }
    Q[n * HSZ + j] = q * 0.70710678118654752f;
    int hh = j >> 1, d = j & 1;
    Kt[hh * (NN * 2) + n * 2 + d] = k;
    Vt[hh * (NN * 2) + n * 2 + d] = v;
}

// ---- attention: one wave handles 8 queries of one head; K/V streamed once ----
__global__ void k_attn(const float* __restrict__ Q, const float* __restrict__ Kt,
                       const float* __restrict__ Vt, float* __restrict__ ao) {
    int gtid = blockIdx.x * 256 + threadIdx.x;
    int wid = gtid >> 6;
    int lane = gtid & 63;
    int hh = wid >> 8;          // 256 waves per head
    int q0 = (wid & 255) * 8;   // 8 queries per wave
    const float2* K2 = (const float2*)Kt + hh * NN;
    const float2* V2 = (const float2*)Vt + hh * NN;
    float qx[8], qy[8];
#pragma unroll
    for (int i = 0; i < 8; ++i) {
        float2 qq = ((const float2*)Q)[(q0 + i) * NH + hh];
        qx[i] = qq.x;
        qy[i] = qq.y;
    }
    float sm[8], a0[8], a1[8];
#pragma unroll
    for (int i = 0; i < 8; ++i) { sm[i] = 0.f; a0[i] = 0.f; a1[i] = 0.f; }
#pragma unroll 2
    for (int it = 0; it < NN / 64; ++it) {
        int mm = it * 64 + lane;
        float2 kk = K2[mm];
        float2 vv = V2[mm];
#pragma unroll
        for (int i = 0; i < 8; ++i) {
            float p = __expf(qx[i] * kk.x + qy[i] * kk.y);
            sm[i] += p;
            a0[i] += p * vv.x;
            a1[i] += p * vv.y;
        }
    }
#pragma unroll
    for (int i = 0; i < 8; ++i) {
#pragma unroll
        for (int off = 32; off > 0; off >>= 1) {
            sm[i] += __shfl_xor(sm[i], off);
            a0[i] += __shfl_xor(a0[i], off);
            a1[i] += __shfl_xor(a1[i], off);
        }
        if (lane == 0) {
            float rs = 1.f / sm[i];
            ((float2*)ao)[(q0 + i) * NH + hh] = make_float2(a0[i] * rs, a1[i] * rs);
        }
    }
}

// ---- O-projection + BN partial column sums (atomics) ----
__global__ void k_oproj(const float* __restrict__ ao, const float* __restrict__ ow,
                        const float* __restrict__ ob, float* __restrict__ X,
                        float* __restrict__ bnbuf) {
    __shared__ float as[256];
    __shared__ float xv[256];
    int tid = threadIdx.x;
    int row0 = blockIdx.x * 8;
    as[tid] = ao[row0 * HSZ + tid];
    __syncthreads();
    int r = tid >> 5, j = tid & 31;
    float a = ob[j];
#pragma unroll
    for (int c = 0; c < HSZ; ++c) a += as[r * HSZ + c] * ow[c * HSZ + j];
    X[(row0 + r) * HSZ + j] = a;
    xv[tid] = a;
    __syncthreads();
    if (tid < HSZ) {
        float s = 0.f, q = 0.f;
#pragma unroll
        for (int rr = 0; rr < 8; ++rr) {
            float v = xv[rr * HSZ + tid];
            s += v;
            q += v * v;
        }
        atomicAdd(&bnbuf[tid], s);
        atomicAdd(&bnbuf[HSZ + tid], q);
    }
}

// ---- BN apply + MLP + scoring head + sigmoid ----
__global__ void k_tail(const float* __restrict__ X, const float* __restrict__ bnbuf,
                       const float* __restrict__ bn_g, const float* __restrict__ bn_b,
                       const float* __restrict__ m1w, const float* __restrict__ m1b,
                       const float* __restrict__ m2w, const float* __restrict__ m2b,
                       const float* __restrict__ w001, const float* __restrict__ b001,
                       const float* __restrict__ w01, const float* __restrict__ b01,
                       const float* __restrict__ w1, const float* __restrict__ b1,
                       const float* __restrict__ w2, const float* __restrict__ b2,
                       float* __restrict__ out) {
    int n = blockIdx.x * 256 + threadIdx.x;
    const float invN = 1.f / NN;
    float x[HSZ];
#pragma unroll
    for (int i = 0; i < HSZ; ++i) {
        float mu = bnbuf[i] * invN;
        float var = bnbuf[HSZ + i] * invN - mu * mu;
        float rstd = rsqrtf(var + 1e-5f);
        x[i] = (X[n * HSZ + i] - mu) * rstd * bn_g[i] + bn_b[i];
    }
    float y[16];
#pragma unroll
    for (int j = 0; j < 16; ++j) {
        float a = m1b[j];
#pragma unroll
        for (int i = 0; i < HSZ; ++i) a += x[i] * m1w[i * 16 + j];
        y[j] = fmaxf(a, 0.f);
    }
    float z[HSZ];
#pragma unroll
    for (int j = 0; j < HSZ; ++j) {
        float a = m2b[j];
#pragma unroll
        for (int i = 0; i < 16; ++i) a += y[i] * m2w[i * HSZ + j];
        z[j] = fmaxf(a, 0.f);
    }
    float a16[16];
#pragma unroll
    for (int j = 0; j < 16; ++j) {
        float a = b001[j];
#pragma unroll
        for (int i = 0; i < HSZ; ++i) a += z[i] * w001[i * 16 + j];
        a16[j] = a > 0.f ? a : 0.01f * a;
    }
    float b8[8];
#pragma unroll
    for (int j = 0; j < 8; ++j) {
        float a = b01[j];
#pragma unroll
        for (int i = 0; i < 16; ++i) a += a16[i] * w01[i * 8 + j];
        b8[j] = a > 0.f ? a : 0.01f * a;
    }
    float c4[4];
#pragma unroll
    for (int j = 0; j < 4; ++j) {
        float a = b1[j];
#pragma unroll
        for (int i = 0; i < 8; ++i) a += b8[i] * w1[i * 4 + j];
        c4[j] = a > 0.f ? a : 0.01f * a;
    }
    float d = b2[0];
#pragma unroll
    for (int i = 0; i < 4; ++i) d += c4[i] * w2[i];
    out[n] = 1.f / (1.f + __expf(-d));
}

extern "C" void kernel_launch(void* const* d_in, const int* in_sizes, int n_in,
                              void* d_out, int out_size, void* d_ws, size_t ws_size,
                              hipStream_t stream) {
    const float* features = (const float*)d_in[0];
    const int* src = (const int*)d_in[1];
    const int* dst = (const int*)d_in[2];
    const float* W1 = (const float*)d_in[3];
    const float* al1 = (const float*)d_in[4];
    const float* ar1 = (const float*)d_in[5];
    const float* bg1 = (const float*)d_in[6];
    const float* W2 = (const float*)d_in[7];
    const float* al2 = (const float*)d_in[8];
    const float* ar2 = (const float*)d_in[9];
    const float* bg2 = (const float*)d_in[10];
    const float* qw = (const float*)d_in[11];
    const float* qb = (const float*)d_in[12];
    const float* kw = (const float*)d_in[13];
    const float* kb = (const float*)d_in[14];
    const float* vw = (const float*)d_in[15];
    const float* vb = (const float*)d_in[16];
    const float* ow = (const float*)d_in[17];
    const float* ob = (const float*)d_in[18];
    const float* bn_g = (const float*)d_in[19];
    const float* bn_b = (const float*)d_in[20];
    const float* m1w = (const float*)d_in[21];
    const float* m1b = (const float*)d_in[22];
    const float* m2w = (const float*)d_in[23];
    const float* m2b = (const float*)d_in[24];
    const float* w001 = (const float*)d_in[25];
    const float* b001 = (const float*)d_in[26];
    const float* w01 = (const float*)d_in[27];
    const float* b01 = (const float*)d_in[28];
    const float* w1 = (const float*)d_in[29];
    const float* b1 = (const float*)d_in[30];
    const float* w2 = (const float*)d_in[31];
    const float* b2 = (const float*)d_in[32];

    int E = in_sizes[1];

    float* ws = (float*)d_ws;
    float* feat = ws;                 // NN*32
    float* el = feat + NN * HSZ;      // NN*16
    float* er = el + NN * NH;         // NN*16
    float* h1 = er + NN * NH;         // NN*32
    float* h2 = h1 + NN * HSZ;        // NN*32
    float* Q = h2 + NN * HSZ;         // NN*32
    float* Kt = Q + NN * HSZ;         // NN*32
    float* Vt = Kt + NN * HSZ;        // NN*32
    float* ao = Vt + NN * HSZ;        // NN*32
    float* X = ao + NN * HSZ;         // NN*32
    float* bnbuf = X + NN * HSZ;      // 64
    int* cnt = (int*)(bnbuf + 64);    // NN
    int* cur = cnt + NN;              // NN
    int* off = cur + NN;              // NN+1
    int* adj = off + NN + 1;          // E

    dim3 b256(256);
    int gE = (E + 255) / 256;

    // GAT layer 1 features (+ zero CSR counters / bnbuf)
    k_gat1<<<NN, b256, 0, stream>>>(features, W1, al1, ar1, feat, el, er, cnt, cur, bnbuf);
    // CSR build (graph shared by both layers)
    k_hist<<<gE, b256, 0, stream>>>(E, dst, cnt);
    k_scan<<<1, b256, 0, stream>>>(cnt, off, E);
    k_scatter<<<gE, b256, 0, stream>>>(E, src, dst, off, cur, adj);
    // layer-1 segment softmax/aggregate -> h1
    k_seg<<<(NN * NH) / 256, b256, 0, stream>>>(off, adj, el, er, feat, bg1, h1);
    // layer-2 features + segment -> h2
    k_gat2<<<NN / 8, b256, 0, stream>>>(h1, W2, al2, ar2, feat, el, er);
    k_seg<<<(NN * NH) / 256, b256, 0, stream>>>(off, adj, el, er, feat, bg2, h2);
    // dense MHA
    k_qkv<<<NN / 8, b256, 0, stream>>>(h2, qw, qb, kw, kb, vw, vb, Q, Kt, Vt);
    k_attn<<<(NN * NH) / (8 * 4), b256, 0, stream>>>(Q, Kt, Vt, ao);
    k_oproj<<<NN / 8, b256, 0, stream>>>(ao, ow, ob, X, bnbuf);
    // BN apply + MLP + head
    k_tail<<<NN / 256, b256, 0, stream>>>(X, bnbuf, bn_g, bn_b, m1w, m1b, m2w, m2b,
                                          w001, b001, w01, b01, w1, b1, w2, b2,
                                          (float*)d_out);
}